// Round 1
// baseline (968.393 us; speedup 1.0000x reference)
//
#include <hip/hip_runtime.h>
#include <cstdint>
#include <cstddef>

// Net: out = sign( BN_train( sign(x)@sign(W1)^T ) clipped ) @ sign(W4)^T
// B=8192, K=16384, H=384, O=10.  All outputs are exact small integers.
//
// Pipeline:
//  K0  prep_w1:   W1 fp32 -> fp8(+-1, e4m3) chunk-major swizzled layout (ws)
//  memset          stats accumulators = 0
//  K1  gemm1:     h = sign(x)@sign(W1)^T via fp8 MFMA, x read once (512MB)
//  K2  colstats:  per-column sum / sumsq in fp64 (exact) via atomics
//  K2b finalize:  mean, gamma/sqrt(var+eps) in fp64; sign(W4) table
//  K3  head:      per-row sign((h-mean)*coef+beta) @ sign(W4)^T -> out

typedef float v4f __attribute__((ext_vector_type(4)));

#define BATCH   8192
#define KDIM    16384
#define HID     384
#define OUT_F   10
#define BK      64              // K-chunk per iteration
#define MT      32              // rows per block
#define NITER   (KDIM / BK)     // 256
#define CHUNK_B (HID * BK)      // 24576 bytes of fp8 W1 per K-chunk

// ---- ws layout (bytes) ----
#define WS_W1C   0
#define WS_H     (6291456)                  // float h[8192][384] = 12582912 B
#define WS_GSUM  (WS_H + 12582912)          // double[384]
#define WS_GSQ   (WS_GSUM + 3072)           // double[384]
#define WS_MEAN  (WS_GSQ + 3072)            // double[384]
#define WS_COEF  (WS_MEAN + 3072)           // double[384]
#define WS_SW4   (WS_COEF + 3072)           // float[3840]

__device__ __forceinline__ uint32_t pack_sign4(v4f v) {
    uint32_t p = 0;
#pragma unroll
    for (int i = 0; i < 4; ++i) {
        uint32_t u = __float_as_uint(v[i]);
        // +1 -> 0x38, -1 -> 0xB8 (fp8 e4m3), exact 0 stays 0 (matches jnp.sign)
        uint32_t b = ((u & 0x7fffffffu) == 0u) ? 0u : (0x38u | ((u >> 24) & 0x80u));
        p |= b << (8 * i);
    }
    return p;
}

// K0: binarize W1 into fp8, chunk-major [256][384][64] with XOR-swizzled
// 8B granules so the GEMM's B-fragment ds_read_b64 is ~conflict-free and the
// staging copy is one linear global_load_lds region per K-chunk.
__global__ void prep_w1(const float* __restrict__ W1, uint8_t* __restrict__ W1c) {
    size_t e = ((size_t)blockIdx.x * blockDim.x + threadIdx.x) * 4;
    int n = (int)(e / KDIM);
    int k = (int)(e & (KDIM - 1));
    v4f w = *(const v4f*)(W1 + e);
    uint32_t p = pack_sign4(w);
    int chunk = k >> 6;
    int kin = k & 63;
    int gx = (kin >> 3) ^ (n & 7);
    *(uint32_t*)(W1c + (size_t)chunk * CHUNK_B + n * 64 + gx * 8 + (kin & 7)) = p;
}

__device__ __forceinline__ void gll16(const void* g, void* l) {
    __builtin_amdgcn_global_load_lds(
        (__attribute__((address_space(1))) void*)(void*)(g),
        (__attribute__((address_space(3))) void*)(l),
        16, 0, 0);
}

// K1: main binary GEMM. 256 blocks x 512 threads, Mtile=32, N=384 full.
__global__ __launch_bounds__(512, 2) void gemm1(const float* __restrict__ x,
                                                const uint8_t* __restrict__ W1c,
                                                float* __restrict__ h) {
    __shared__ __align__(16) uint8_t Ws[2][CHUNK_B];   // 2 x 24576
    __shared__ __align__(16) uint8_t Xs[2][MT * 72];   // 2 x 2304 (stride 64+8 pad)

    const int t    = threadIdx.x;
    const int wave = t >> 6;
    const int lane = t & 63;
    const int q    = lane >> 4;   // 0..3
    const int l15  = lane & 15;
    const int m0   = blockIdx.x * MT;

    // x staging: thread -> (row = t>>4, 4 consecutive k)
    const int xrow = t >> 4;          // 0..31
    const int xk4  = (t & 15) * 4;    // 0..60
    const float* xp = x + (size_t)(m0 + xrow) * KDIM + xk4;

    v4f acc[2][3];
#pragma unroll
    for (int mt = 0; mt < 2; ++mt)
#pragma unroll
        for (int nt = 0; nt < 3; ++nt)
            acc[mt][nt] = v4f{0.f, 0.f, 0.f, 0.f};

    // ---- prologue: stage iter 0 into buffer 0 ----
    {
        const uint8_t* src = W1c + (size_t)wave * 3072 + (size_t)lane * 16;
#pragma unroll
        for (int r = 0; r < 3; ++r)
            gll16(src + r * 1024, &Ws[0][wave * 3072 + r * 1024]);
        v4f xv = *(const v4f*)(xp);
        *(uint32_t*)&Xs[0][xrow * 72 + xk4] = pack_sign4(xv);
    }
    __syncthreads();

#pragma unroll 2
    for (int it = 0; it < NITER; ++it) {
        const int cur = it & 1;
        const int nxt = cur ^ 1;
        const bool more = (it + 1) < NITER;
        v4f xv;
        if (more) {
            const uint8_t* src = W1c + (size_t)(it + 1) * CHUNK_B
                               + (size_t)wave * 3072 + (size_t)lane * 16;
#pragma unroll
            for (int r = 0; r < 3; ++r)
                gll16(src + r * 1024, &Ws[nxt][wave * 3072 + r * 1024]);
            xv = *(const v4f*)(xp + (size_t)(it + 1) * BK);
        }

        // compute on cur buffer
#pragma unroll
        for (int s = 0; s < 2; ++s) {
            long long a[2], b[3];
#pragma unroll
            for (int mt = 0; mt < 2; ++mt) {
                int m = mt * 16 + l15;
                a[mt] = *(const long long*)&Xs[cur][m * 72 + s * 32 + q * 8];
            }
#pragma unroll
            for (int nt = 0; nt < 3; ++nt) {
                int n = wave * 48 + nt * 16 + l15;
                int g = (s * 4 + q) ^ (n & 7);
                b[nt] = *(const long long*)&Ws[cur][n * 64 + g * 8];
            }
#pragma unroll
            for (int mt = 0; mt < 2; ++mt)
#pragma unroll
                for (int nt = 0; nt < 3; ++nt)
                    acc[mt][nt] = __builtin_amdgcn_mfma_f32_16x16x32_fp8_fp8(
                        a[mt], b[nt], acc[mt][nt], 0, 0, 0);
        }

        if (more) {
            *(uint32_t*)&Xs[nxt][xrow * 72 + xk4] = pack_sign4(xv);
        }
        __syncthreads();  // drains vmcnt (incl. global_load_lds) + lgkm
    }

    // epilogue: C/D layout col=lane&15, row=(lane>>4)*4+reg  [m89/m121]
#pragma unroll
    for (int mt = 0; mt < 2; ++mt)
#pragma unroll
        for (int nt = 0; nt < 3; ++nt)
#pragma unroll
            for (int r = 0; r < 4; ++r) {
                int row = m0 + mt * 16 + q * 4 + r;
                int col = wave * 48 + nt * 16 + l15;
                h[(size_t)row * HID + col] = acc[mt][nt][r];
            }
}

// K2: per-column sum / sumsq in fp64 (exact: integer values)
__global__ void colstats(const float* __restrict__ h,
                         double* __restrict__ gsum, double* __restrict__ gsq) {
    int j  = threadIdx.x;          // 0..383, coalesced across threads
    int r0 = blockIdx.x * 128;
    double s = 0.0, sq = 0.0;
    for (int r = 0; r < 128; ++r) {
        double v = (double)h[(size_t)(r0 + r) * HID + j];
        s += v;
        sq += v * v;
    }
    atomicAdd(&gsum[j], s);
    atomicAdd(&gsq[j], sq);
}

// K2b: finalize stats + sign(W4) table
__global__ void finalize(const double* __restrict__ gsum, const double* __restrict__ gsq,
                         const float* __restrict__ gamma, const float* __restrict__ W4,
                         double* __restrict__ meanArr, double* __restrict__ coefArr,
                         float* __restrict__ sW4) {
    int j = threadIdx.x;
    double mean = gsum[j] * (1.0 / (double)BATCH);
    double var  = gsq[j] * (1.0 / (double)BATCH) - mean * mean;
    meanArr[j] = mean;
    coefArr[j] = (double)gamma[j] / sqrt(var + 1e-5);
#pragma unroll
    for (int o = 0; o < OUT_F; ++o) {
        float w = W4[o * HID + j];
        sW4[o * HID + j] = (w > 0.f) ? 1.f : ((w < 0.f) ? -1.f : 0.f);
    }
}

// K3: per-row normalize -> sign -> tiny GEMM with sign(W4). One wave per row.
__global__ __launch_bounds__(256) void head(const float* __restrict__ h,
                                            const double* __restrict__ meanArr,
                                            const double* __restrict__ coefArr,
                                            const float* __restrict__ beta,
                                            const float* __restrict__ sW4,
                                            float* __restrict__ out) {
    int wave = threadIdx.x >> 6;
    int lane = threadIdx.x & 63;
    int b = blockIdx.x * 4 + wave;
    float a[OUT_F];
#pragma unroll
    for (int o = 0; o < OUT_F; ++o) a[o] = 0.f;
#pragma unroll
    for (int i = 0; i < 6; ++i) {
        int j = lane + i * 64;
        double v = ((double)h[(size_t)b * HID + j] - meanArr[j]) * coefArr[j]
                 + (double)beta[j];
        // clip(-1,1) preserves sign; sign(0)=0
        float s = (v > 0.0) ? 1.f : ((v < 0.0) ? -1.f : 0.f);
#pragma unroll
        for (int o = 0; o < OUT_F; ++o) a[o] += s * sW4[o * HID + j];
    }
#pragma unroll
    for (int o = 0; o < OUT_F; ++o) {
#pragma unroll
        for (int off = 32; off > 0; off >>= 1) a[o] += __shfl_down(a[o], off);
    }
    if (lane == 0) {
#pragma unroll
        for (int o = 0; o < OUT_F; ++o) out[(size_t)b * OUT_F + o] = a[o];
    }
}

extern "C" void kernel_launch(void* const* d_in, const int* in_sizes, int n_in,
                              void* d_out, int out_size, void* d_ws, size_t ws_size,
                              hipStream_t stream) {
    const float* x     = (const float*)d_in[0];
    const float* W1    = (const float*)d_in[1];
    const float* gamma = (const float*)d_in[2];
    const float* beta  = (const float*)d_in[3];
    const float* W4    = (const float*)d_in[4];
    float* out = (float*)d_out;

    uint8_t* ws = (uint8_t*)d_ws;
    uint8_t* W1c      = ws + WS_W1C;
    float*   h        = (float*)(ws + WS_H);
    double*  gsum     = (double*)(ws + WS_GSUM);
    double*  gsq      = (double*)(ws + WS_GSQ);
    double*  meanArr  = (double*)(ws + WS_MEAN);
    double*  coefArr  = (double*)(ws + WS_COEF);
    float*   sW4      = (float*)(ws + WS_SW4);

    // K0: 6291456 elems / 4 per thread / 256 per block = 6144 blocks
    prep_w1<<<6144, 256, 0, stream>>>(W1, W1c);
    hipMemsetAsync(gsum, 0, 2 * HID * sizeof(double), stream);
    gemm1<<<BATCH / MT, 512, 0, stream>>>(x, W1c, h);
    colstats<<<BATCH / 128, HID, 0, stream>>>(h, gsum, gsq);
    finalize<<<1, HID, 0, stream>>>(gsum, gsq, gamma, W4, meanArr, coefArr, sW4);
    head<<<BATCH / 4, 256, 0, stream>>>(h, meanArr, coefArr, beta, sW4, out);
}

// Round 2
// 795.350 us; speedup vs baseline: 1.2176x; 1.2176x over previous
//
#include <hip/hip_runtime.h>
#include <cstdint>
#include <cstddef>

// Net: out = sign( BN_train( sign(x)@sign(W1)^T ) clipped ) @ sign(W4)^T
// B=8192, K=16384, H=384, O=10.  All values exact small integers.
//
// R2 structure: W1 fragments go straight to REGISTERS (no sharing between
// waves -> LDS staging was pure overhead + bank conflicts). LDS only holds
// the 4.6KB x double-buffer. 256-thread blocks, MT=32, split-K=4 (exact fp32
// atomic accumulate) -> grid 1024 = 4 blocks/CU for cross-block latency
// overlap (R1 had exactly 1 block/CU = zero overlap, 394us vs ~90us floor).

typedef float v4f __attribute__((ext_vector_type(4)));
typedef long long v2l __attribute__((ext_vector_type(2)));

#define BATCH   8192
#define KDIM    16384
#define HID     384
#define OUT_F   10
#define BK      64
#define MT      32
#define SPLITK  4
#define KPB     (KDIM / SPLITK)      // 4096
#define NIT     (KPB / BK)           // 64
#define WCHUNK  (HID * BK)           // 24576 B of fp8 W1 per K-chunk

// ---- ws layout (bytes) ----
#define WS_W1C   0
#define WS_H     (6291456)                  // float h[8192][384] = 12582912 B
#define WS_GSUM  (WS_H + 12582912)          // double[384]
#define WS_GSQ   (WS_GSUM + 3072)           // double[384]
#define WS_MEAN  (WS_GSQ + 3072)            // double[384]
#define WS_COEF  (WS_MEAN + 3072)           // double[384]
#define WS_SW4   (WS_COEF + 3072)           // float[3840]

__device__ __forceinline__ uint32_t pack_sign4(v4f v) {
    uint32_t p = 0;
#pragma unroll
    for (int i = 0; i < 4; ++i) {
        uint32_t u = __float_as_uint(v[i]);
        // +1 -> 0x38, -1 -> 0xB8 (fp8 e4m3), exact 0 stays 0 (matches jnp.sign)
        uint32_t b = ((u & 0x7fffffffu) == 0u) ? 0u : (0x38u | ((u >> 24) & 0x80u));
        p |= b << (8 * i);
    }
    return p;
}

// K0: binarize W1 -> fp8, layout [it(256)][col(384)][q(4)][16B], where the
// 16B granule for (col,q) = k-bytes {q*8..q*8+7} ++ {32+q*8..32+q*8+7}.
// Lane (q,l15) of a wave then loads its whole 16x16x32 B-fragment pair
// (s=0,1) with ONE dwordx4, and a wave's 64 lanes cover 1024 contiguous B.
__global__ void prep_w1(const float* __restrict__ W1, uint8_t* __restrict__ W1c) {
    size_t e = ((size_t)blockIdx.x * blockDim.x + threadIdx.x) * 4;
    int c   = (int)(e >> 14);         // / 16384
    int k   = (int)(e & 16383);
    int it  = k >> 6;
    int kin = k & 63;
    int s   = kin >> 5;
    int q   = (kin >> 3) & 3;
    int j   = kin & 7;                // 0 or 4
    v4f w = *(const v4f*)(W1 + e);
    uint32_t p = pack_sign4(w);
    *(uint32_t*)(W1c + (((size_t)it * HID + c) * 4 + q) * 16 + s * 8 + j) = p;
}

// K1: binary GEMM. grid = (8192/32)*SPLITK = 1024 blocks x 256 threads.
// Each wave owns 96 columns (6 n-tiles); W fragments live in registers,
// double-buffered; x staged through tiny LDS double buffer.
__global__ __launch_bounds__(256, 4) void gemm1(const float* __restrict__ x,
                                                const uint8_t* __restrict__ W1c,
                                                float* __restrict__ h) {
    __shared__ __align__(16) uint8_t Xs[2][MT * 72];   // 2 x 2304 B

    const int t    = threadIdx.x;
    const int wave = t >> 6;
    const int lane = t & 63;
    const int q    = lane >> 4;    // 0..3
    const int l15  = lane & 15;
    const int kblk = blockIdx.x & (SPLITK - 1);
    const int m0   = (blockIdx.x >> 2) * MT;

    // x staging: thread -> (row = t>>3, 8 consecutive k), 32B per thread/iter
    const int xrow = t >> 3;           // 0..31
    const int xk8  = (t & 7) * 8;      // 0..56
    const float* xp = x + (size_t)(m0 + xrow) * KDIM + (size_t)kblk * KPB + xk8;

    // per-lane W fragment base (iter stride = WCHUNK, nt stride = 1024B)
    const uint8_t* wp = W1c + (size_t)kblk * ((size_t)NIT * WCHUNK)
                      + (((size_t)(wave * 96 + l15)) * 4 + q) * 16;

    v4f acc[2][6];
#pragma unroll
    for (int mt = 0; mt < 2; ++mt)
#pragma unroll
        for (int nt = 0; nt < 6; ++nt)
            acc[mt][nt] = v4f{0.f, 0.f, 0.f, 0.f};

    v2l wc[6];
    // ---- prologue: iter 0 ----
    {
#pragma unroll
        for (int nt = 0; nt < 6; ++nt)
            wc[nt] = *(const v2l*)(wp + nt * 1024);
        v4f xa = *(const v4f*)(xp);
        v4f xb = *(const v4f*)(xp + 4);
        uint2 pk; pk.x = pack_sign4(xa); pk.y = pack_sign4(xb);
        *(uint2*)&Xs[0][xrow * 72 + xk8] = pk;
    }
    __syncthreads();

#pragma unroll 2
    for (int it = 0; it < NIT; ++it) {
        const int cur = it & 1;
        const bool more = (it + 1) < NIT;
        v2l wn[6];
        v4f xa, xb;
        if (more) {
            const uint8_t* wpn = wp + (size_t)(it + 1) * WCHUNK;
#pragma unroll
            for (int nt = 0; nt < 6; ++nt)
                wn[nt] = *(const v2l*)(wpn + nt * 1024);
            xa = *(const v4f*)(xp + (size_t)(it + 1) * BK);
            xb = *(const v4f*)(xp + (size_t)(it + 1) * BK + 4);
        }

        // compute it from Xs[cur] + wc
#pragma unroll
        for (int s = 0; s < 2; ++s) {
            long long a[2];
#pragma unroll
            for (int mt = 0; mt < 2; ++mt)
                a[mt] = *(const long long*)&Xs[cur][(mt * 16 + l15) * 72 + s * 32 + q * 8];
#pragma unroll
            for (int nt = 0; nt < 6; ++nt)
#pragma unroll
                for (int mt = 0; mt < 2; ++mt)
                    acc[mt][nt] = __builtin_amdgcn_mfma_f32_16x16x32_fp8_fp8(
                        a[mt], wc[nt][s], acc[mt][nt], 0, 0, 0);
        }

        if (more) {
            uint2 pk; pk.x = pack_sign4(xa); pk.y = pack_sign4(xb);
            *(uint2*)&Xs[cur ^ 1][xrow * 72 + xk8] = pk;
#pragma unroll
            for (int nt = 0; nt < 6; ++nt) wc[nt] = wn[nt];
        }
        __syncthreads();
    }

    // epilogue: C/D layout col=lane&15, row=(lane>>4)*4+reg  [m89/m121]
    // split-K partials are integers |p|<=4096 -> fp32 atomicAdd is exact.
#pragma unroll
    for (int nt = 0; nt < 6; ++nt) {
        const int col = wave * 96 + nt * 16 + l15;
#pragma unroll
        for (int mt = 0; mt < 2; ++mt)
#pragma unroll
            for (int r = 0; r < 4; ++r)
                atomicAdd(&h[(size_t)(m0 + mt * 16 + q * 4 + r) * HID + col],
                          acc[mt][nt][r]);
    }
}

// K2: per-column sum / sumsq in fp64 (exact: integer values). 512 blocks.
__global__ void colstats(const float* __restrict__ h,
                         double* __restrict__ gsum, double* __restrict__ gsq) {
    int j  = threadIdx.x;          // 0..383, coalesced
    int r0 = blockIdx.x * 16;
    double s = 0.0, sq = 0.0;
#pragma unroll
    for (int r = 0; r < 16; ++r) {
        double v = (double)h[(size_t)(r0 + r) * HID + j];
        s += v;
        sq += v * v;
    }
    atomicAdd(&gsum[j], s);
    atomicAdd(&gsq[j], sq);
}

// K2b: finalize stats + sign(W4) table
__global__ void finalize(const double* __restrict__ gsum, const double* __restrict__ gsq,
                         const float* __restrict__ gamma, const float* __restrict__ W4,
                         double* __restrict__ meanArr, double* __restrict__ coefArr,
                         float* __restrict__ sW4) {
    int j = threadIdx.x;
    double mean = gsum[j] * (1.0 / (double)BATCH);
    double var  = gsq[j] * (1.0 / (double)BATCH) - mean * mean;
    meanArr[j] = mean;
    coefArr[j] = (double)gamma[j] / sqrt(var + 1e-5);
#pragma unroll
    for (int o = 0; o < OUT_F; ++o) {
        float w = W4[o * HID + j];
        sW4[o * HID + j] = (w > 0.f) ? 1.f : ((w < 0.f) ? -1.f : 0.f);
    }
}

// K3: per-row normalize -> sign -> tiny GEMM with sign(W4). One wave per row.
__global__ __launch_bounds__(256) void head(const float* __restrict__ h,
                                            const double* __restrict__ meanArr,
                                            const double* __restrict__ coefArr,
                                            const float* __restrict__ beta,
                                            const float* __restrict__ sW4,
                                            float* __restrict__ out) {
    int wave = threadIdx.x >> 6;
    int lane = threadIdx.x & 63;
    int b = blockIdx.x * 4 + wave;
    float a[OUT_F];
#pragma unroll
    for (int o = 0; o < OUT_F; ++o) a[o] = 0.f;
#pragma unroll
    for (int i = 0; i < 6; ++i) {
        int j = lane + i * 64;
        double v = ((double)h[(size_t)b * HID + j] - meanArr[j]) * coefArr[j]
                 + (double)beta[j];
        // clip(-1,1) preserves sign; sign(0)=0
        float s = (v > 0.0) ? 1.f : ((v < 0.0) ? -1.f : 0.f);
#pragma unroll
        for (int o = 0; o < OUT_F; ++o) a[o] += s * sW4[o * HID + j];
    }
#pragma unroll
    for (int o = 0; o < OUT_F; ++o) {
#pragma unroll
        for (int off = 32; off > 0; off >>= 1) a[o] += __shfl_down(a[o], off);
    }
    if (lane == 0) {
#pragma unroll
        for (int o = 0; o < OUT_F; ++o) out[(size_t)b * OUT_F + o] = a[o];
    }
}

extern "C" void kernel_launch(void* const* d_in, const int* in_sizes, int n_in,
                              void* d_out, int out_size, void* d_ws, size_t ws_size,
                              hipStream_t stream) {
    const float* x     = (const float*)d_in[0];
    const float* W1    = (const float*)d_in[1];
    const float* gamma = (const float*)d_in[2];
    const float* beta  = (const float*)d_in[3];
    const float* W4    = (const float*)d_in[4];
    float* out = (float*)d_out;

    uint8_t* ws = (uint8_t*)d_ws;
    uint8_t* W1c     = ws + WS_W1C;
    float*   h       = (float*)(ws + WS_H);
    double*  gsum    = (double*)(ws + WS_GSUM);
    double*  gsq     = (double*)(ws + WS_GSQ);
    double*  meanArr = (double*)(ws + WS_MEAN);
    double*  coefArr = (double*)(ws + WS_COEF);
    float*   sW4     = (float*)(ws + WS_SW4);

    prep_w1<<<6144, 256, 0, stream>>>(W1, W1c);
    // zero h (needed: split-K atomic accumulate) + gsum + gsq in one memset
    hipMemsetAsync(ws + WS_H, 0, 12582912 + 2 * HID * sizeof(double), stream);
    gemm1<<<(BATCH / MT) * SPLITK, 256, 0, stream>>>(x, W1c, h);
    colstats<<<BATCH / 16, HID, 0, stream>>>(h, gsum, gsq);
    finalize<<<1, HID, 0, stream>>>(gsum, gsq, gamma, W4, meanArr, coefArr, sW4);
    head<<<BATCH / 4, 256, 0, stream>>>(h, meanArr, coefArr, beta, sW4, out);
}